// Round 11
// baseline (170.176 us; speedup 1.0000x reference)
//
#include <hip/hip_runtime.h>
#include <hip/hip_bf16.h>

#define B 16
#define L 128
#define H 256
#define H2 512
#define P 16
#define EPSF 1e-8f
#define LDSTR2 264   // shorts per 256-col bf16 LDS row (+8 pad)

typedef __attribute__((ext_vector_type(8))) short short8;
typedef __attribute__((ext_vector_type(4))) short short4v;
typedef __attribute__((ext_vector_type(4))) float f32x4;

__device__ __forceinline__ short f2bf(float x) {
    unsigned u = __builtin_bit_cast(unsigned, x);
    u += 0x7fffu + ((u >> 16) & 1u);   // RNE; inputs finite
    return (short)(u >> 16);
}
__device__ __forceinline__ float bf2f(short s) {
    unsigned u = ((unsigned)(unsigned short)s) << 16;
    return __builtin_bit_cast(float, u);
}
__device__ __forceinline__ short8 pack8(float4 x, float4 y) {
    short8 s;
    s[0] = f2bf(x.x); s[1] = f2bf(x.y); s[2] = f2bf(x.z); s[3] = f2bf(x.w);
    s[4] = f2bf(y.x); s[5] = f2bf(y.y); s[6] = f2bf(y.z); s[7] = f2bf(y.w);
    return s;
}
__device__ __forceinline__ float dot4(float4 v) {
    return v.x * v.x + v.y * v.y + v.z * v.z + v.w * v.w;
}
__device__ __forceinline__ float4 mul4(float4 a, float4 b) {
    return make_float4(a.x * b.x, a.y * b.y, a.z * b.z, a.w * b.w);
}

// ---- K1: attention, wave-per-16x16-tile, no LDS (R9-verbatim) --------------
__global__ void __launch_bounds__(64) k_att_v3(
        const float* __restrict__ q1, const float* __restrict__ q2,
        float* __restrict__ att_fw, float* __restrict__ att_bw,
        float* __restrict__ attsum) {
    int bx = blockIdx.x;
    int b = bx >> 1, dir = bx & 1;
    int m0 = blockIdx.y * 16, n0 = blockIdx.z * 16;
    int l = threadIdx.x, q = l >> 4, coll = l & 15;
    size_t bL = (size_t)b * L;

    const float* arow = q1 + (bL + m0 + coll) * H2 + dir * H;
    const float* brow = q2 + (bL + n0 + coll) * H2 + dir * H;

    f32x4 acc = (f32x4){0.f, 0.f, 0.f, 0.f};
    float na = 0.f, nc = 0.f;
#pragma unroll
    for (int ks = 0; ks < 8; ks++) {
        int koff = ks * 32 + q * 8;
        float4 a0 = *(const float4*)(arow + koff);
        float4 a1 = *(const float4*)(arow + koff + 4);
        float4 b0 = *(const float4*)(brow + koff);
        float4 b1 = *(const float4*)(brow + koff + 4);
        na += dot4(a0) + dot4(a1);
        nc += dot4(b0) + dot4(b1);
        short8 af = pack8(a0, a1);
        short8 bf = pack8(b0, b1);
        acc = __builtin_amdgcn_mfma_f32_16x16x32_bf16(af, bf, acc, 0, 0, 0);
    }
    na += __shfl_xor(na, 16); na += __shfl_xor(na, 32);
    nc += __shfl_xor(nc, 16); nc += __shfl_xor(nc, 32);
    float na_s = sqrtf(na), nc_s = sqrtf(nc);

    float* attout = dir ? att_bw : att_fw;
    float rsum[4];
#pragma unroll
    for (int r = 0; r < 4; r++) {
        float nar = __shfl(na_s, (l & 48) + q * 4 + r);
        float den = nar * nc_s;
        den = den > EPSF ? den : EPSF;
        float a = acc[r] / den;
        attout[(bL + m0 + q * 4 + r) * L + n0 + coll] = a;
        rsum[r] = a;
    }
    if (dir == 0) {
#pragma unroll
        for (int off = 1; off < 16; off <<= 1)
#pragma unroll
            for (int r = 0; r < 4; r++)
                rsum[r] += __shfl_xor(rsum[r], off, 16);
        if (coll == 0)
#pragma unroll
            for (int r = 0; r < 4; r++)
                atomicAdd(&attsum[bL + m0 + q * 4 + r], rsum[r]);
    }
}

// ---- K2: weighted mean + max of att*q2; 8 i-rows/block (R9 math) -----------
// Grid (B*2, 16): 4 waves split j (32 each), lane owns float4 h-chunk.
__global__ void __launch_bounds__(256) k_meanmax_v3(
        const float* __restrict__ q2,
        const float* __restrict__ att_fw, const float* __restrict__ att_bw,
        const float* __restrict__ attsum,
        float* __restrict__ mean_fw, float* __restrict__ mean_bw,
        float* __restrict__ maxat_fw, float* __restrict__ maxat_bw) {
    int bd = blockIdx.x;
    int b = bd >> 1, dir = bd & 1;
    int i0 = blockIdx.y * 8;
    int t = threadIdx.x;
    int wave = t >> 6, l = t & 63;
    size_t bL = (size_t)b * L;

    __shared__ float at[8][L];
    __shared__ float Ss[8];
    __shared__ f32x4 red[4][64][4];

    const float* att = dir ? att_bw : att_fw;
    for (int v = t; v < 8 * L; v += 256)
        at[v >> 7][v & 127] = att[(bL + i0 + (v >> 7)) * L + (v & 127)];
    if (t < 8) {
        float s = attsum[bL + i0 + t];
        Ss[t] = s > EPSF ? s : EPSF;
    }
    __syncthreads();

    f32x4 sum[8], mx[8];
#pragma unroll
    for (int r = 0; r < 8; r++) {
        sum[r] = (f32x4){0.f, 0.f, 0.f, 0.f};
        mx[r] = (f32x4){-INFINITY, -INFINITY, -INFINITY, -INFINITY};
    }
    const float* q2b = q2 + bL * H2 + dir * H;
    for (int jj = 0; jj < 32; jj++) {
        int j = wave * 32 + jj;
        float4 c = *(const float4*)(q2b + (size_t)j * H2 + l * 4);
#pragma unroll
        for (int r = 0; r < 8; r++) {
            float w = at[r][j];
            f32x4 v = { w * c.x, w * c.y, w * c.z, w * c.w };
            sum[r] += v;
            mx[r][0] = fmaxf(mx[r][0], v[0]);
            mx[r][1] = fmaxf(mx[r][1], v[1]);
            mx[r][2] = fmaxf(mx[r][2], v[2]);
            mx[r][3] = fmaxf(mx[r][3], v[3]);
        }
    }
    float* meanout = dir ? mean_bw : mean_fw;
    float* maxout = dir ? maxat_bw : maxat_fw;
    for (int rr = 0; rr < 4; rr++) {
        __syncthreads();
        red[wave][l][0] = sum[rr * 2];
        red[wave][l][1] = mx[rr * 2];
        red[wave][l][2] = sum[rr * 2 + 1];
        red[wave][l][3] = mx[rr * 2 + 1];
        __syncthreads();
        if (t < 128) {
            int r2 = t >> 6;
            int lane = t & 63;
            f32x4 s = red[0][lane][r2 * 2];
            f32x4 m = red[0][lane][r2 * 2 + 1];
            for (int w = 1; w < 4; w++) {
                s += red[w][lane][r2 * 2];
                f32x4 m2 = red[w][lane][r2 * 2 + 1];
                m[0] = fmaxf(m[0], m2[0]);
                m[1] = fmaxf(m[1], m2[1]);
                m[2] = fmaxf(m[2], m2[2]);
                m[3] = fmaxf(m[3], m2[3]);
            }
            int row = i0 + rr * 2 + r2;
            float inv = 1.f / Ss[rr * 2 + r2];
            size_t o = (bL + row) * H + lane * 4;
            *(f32x4*)(meanout + o) = s * inv;
            *(f32x4*)(maxout + o) = m;
        }
    }
}

// ---- K3: six cos_full pieces, fp32, float4 loads (R10-verbatim) ------------
__global__ void __launch_bounds__(256) k_cosfull_v4(
        const float* __restrict__ q1, const float* __restrict__ q2,
        const float* __restrict__ mean_fw, const float* __restrict__ mean_bw,
        const float* __restrict__ maxat_fw, const float* __restrict__ maxat_bw,
        const float* __restrict__ W, float* __restrict__ out) {
    int bg = blockIdx.x;
    int b = bg >> 4;
    int i0 = (bg & 15) * 8;
    int piece = blockIdx.y;
    int t = threadIdx.x;
    int p = t >> 4, l = t & 15;
    size_t bL = (size_t)b * L;

    int widx, colb, dir, cstride;
    const float* cptr;
    switch (piece) {
        case 0: widx = 0; colb = 0;   dir = 0; cptr = q2 + (bL + L - 1) * H2;  cstride = 0; break;
        case 1: widx = 1; colb = 16;  dir = 1; cptr = q2 + bL * H2 + H;        cstride = 0; break;
        case 2: widx = 4; colb = 64;  dir = 0; cptr = mean_fw + bL * H;        cstride = H; break;
        case 3: widx = 5; colb = 80;  dir = 1; cptr = mean_bw + bL * H;        cstride = H; break;
        case 4: widx = 6; colb = 96;  dir = 0; cptr = maxat_fw + bL * H;       cstride = H; break;
        default: widx = 7; colb = 112; dir = 1; cptr = maxat_bw + bL * H;      cstride = H; break;
    }
    const float* wrow = W + ((size_t)widx * P + p) * H + l * 16;
    float4 wq[4];
#pragma unroll
    for (int c = 0; c < 4; c++) {
        float4 w4 = *(const float4*)(wrow + c * 4);
        wq[c] = mul4(w4, w4);
    }
    for (int ii = 0; ii < 8; ii++) {
        int i = i0 + ii;
        const float* r1 = q1 + (bL + i) * H2 + dir * H + l * 16;
        const float* crow = cptr + (size_t)i * cstride + l * 16;
        float num = 0, na = 0, nc = 0;
#pragma unroll
        for (int c = 0; c < 4; c++) {
            float4 a = *(const float4*)(r1 + c * 4);
            float4 cc = *(const float4*)(crow + c * 4);
            num += a.x * cc.x * wq[c].x + a.y * cc.y * wq[c].y
                 + a.z * cc.z * wq[c].z + a.w * cc.w * wq[c].w;
            na  += a.x * a.x * wq[c].x + a.y * a.y * wq[c].y
                 + a.z * a.z * wq[c].z + a.w * a.w * wq[c].w;
            nc  += cc.x * cc.x * wq[c].x + cc.y * cc.y * wq[c].y
                 + cc.z * cc.z * wq[c].z + cc.w * cc.w * wq[c].w;
        }
        for (int off = 8; off; off >>= 1) {
            num += __shfl_down(num, off, 16);
            na  += __shfl_down(na,  off, 16);
            nc  += __shfl_down(nc,  off, 16);
        }
        if (l == 0) {
            float den = sqrtf(na) * sqrtf(nc);
            den = den > EPSF ? den : EPSF;
            out[(bL + i) * 128 + colb + p] = num / den;
        }
    }
}

// ---- K4: cos_maxpool — B staged ONCE per (b,dir,p), both m-halves looped ---
// Grid (B*2, P) = 512 blocks, 256 thr / 4 waves. R9-consistent numerics:
// norms from the quantized bf16 values that feed the MFMA.
__global__ void __launch_bounds__(256, 2) k_maxpool_v5(
        const float* __restrict__ q1, const float* __restrict__ q2,
        const float* __restrict__ W, float* __restrict__ out) {
    int bd = blockIdx.x;
    int b = bd >> 1, dir = bd & 1;
    int p = blockIdx.y;
    int t = threadIdx.x;
    int wave = t >> 6, l = t & 63;
    int q = l >> 4, coll = l & 15;
    size_t bL = (size_t)b * L;

    __shared__ short Bs[128 * LDSTR2];
    __shared__ float wf[H];
    __shared__ float ncs[128];

    const float* wbase = W + ((size_t)(2 + dir) * P + p) * H;
    if (t < 64)
        *(float4*)(wf + t * 4) = *(const float4*)(wbase + t * 4);
    __syncthreads();

    // stage full B (128 x 256) w-folded; thread t: row t>>1, col-half (t&1)*32 per kt
    int brow = t >> 1, bc0 = (t & 1) * 32;
    const float* q2b = q2 + bL * H2 + dir * H;
    const float* brp = q2b + (size_t)brow * H2;
    float ncp = 0.f;
#pragma unroll
    for (int kt = 0; kt < 4; kt++) {
        int k0 = kt * 64;
#pragma unroll
        for (int cc = 0; cc < 8; cc++) {
            float4 v = *(const float4*)(brp + k0 + bc0 + cc * 4);
            float4 wv4 = *(const float4*)(wf + k0 + bc0 + cc * 4);
            float4 x = mul4(v, wv4);
            short4v s = { f2bf(x.x), f2bf(x.y), f2bf(x.z), f2bf(x.w) };
            *(short4v*)(Bs + brow * LDSTR2 + k0 + bc0 + cc * 4) = s;
            float f0 = bf2f(s[0]), f1 = bf2f(s[1]), f2v = bf2f(s[2]), f3 = bf2f(s[3]);
            ncp += f0 * f0 + f1 * f1 + f2v * f2v + f3 * f3;
        }
    }
    ncp += __shfl_xor(ncp, 1);
    if ((t & 1) == 0) ncs[brow] = sqrtf(ncp);
    __syncthreads();

    for (int half = 0; half < 2; half++) {
        int m0 = half * 64 + wave * 16;
        const float* arow = q1 + (bL + m0 + coll) * H2 + dir * H;
        f32x4 acc[8];
#pragma unroll
        for (int nt = 0; nt < 8; nt++) acc[nt] = (f32x4){0.f, 0.f, 0.f, 0.f};
        float nap = 0.f;
#pragma unroll
        for (int ks = 0; ks < 8; ks++) {
            int koff = ks * 32 + q * 8;
            float4 a0 = *(const float4*)(arow + koff);
            float4 a1 = *(const float4*)(arow + koff + 4);
            float4 w0 = *(const float4*)(wf + koff);
            float4 w1 = *(const float4*)(wf + koff + 4);
            short8 af = pack8(mul4(a0, w0), mul4(a1, w1));
#pragma unroll
            for (int j = 0; j < 8; j++) {
                float f = bf2f(af[j]);
                nap += f * f;
            }
#pragma unroll
            for (int nt = 0; nt < 8; nt++) {
                short8 bf = *(const short8*)(Bs + (nt * 16 + coll) * LDSTR2 + koff);
                acc[nt] = __builtin_amdgcn_mfma_f32_16x16x32_bf16(af, bf, acc[nt], 0, 0, 0);
            }
        }
        nap += __shfl_xor(nap, 16);
        nap += __shfl_xor(nap, 32);
        float na_s = sqrtf(nap);

        float nar[4];
#pragma unroll
        for (int r = 0; r < 4; r++)
            nar[r] = __shfl(na_s, (l & 48) + q * 4 + r);
        float rmax[4] = {-INFINITY, -INFINITY, -INFINITY, -INFINITY};
#pragma unroll
        for (int nt = 0; nt < 8; nt++) {
            float ncv = ncs[nt * 16 + coll];
#pragma unroll
            for (int r = 0; r < 4; r++) {
                float den = fmaxf(nar[r] * ncv, EPSF);
                rmax[r] = fmaxf(rmax[r], acc[nt][r] / den);
            }
        }
#pragma unroll
        for (int off = 1; off < 16; off <<= 1)
#pragma unroll
            for (int r = 0; r < 4; r++)
                rmax[r] = fmaxf(rmax[r], __shfl_xor(rmax[r], off, 16));
        if (coll == 0)
#pragma unroll
            for (int r = 0; r < 4; r++)
                out[(bL + m0 + q * 4 + r) * 128 + 32 + dir * 16 + p] = rmax[r];
    }
}

extern "C" void kernel_launch(void* const* d_in, const int* in_sizes, int n_in,
                              void* d_out, int out_size, void* d_ws, size_t ws_size,
                              hipStream_t stream) {
    const float* q1 = (const float*)d_in[0];
    const float* q2 = (const float*)d_in[1];
    const float* W  = (const float*)d_in[2];
    float* out = (float*)d_out;

    float* ws = (float*)d_ws;
    float* attsum = ws;                               // 2048
    float* att_fw = attsum + 2048;                    // B*L*L
    float* att_bw = att_fw + (size_t)B * L * L;
    float* mean_fw = att_bw + (size_t)B * L * L;      // B*L*H each
    float* mean_bw = mean_fw + (size_t)B * L * H;
    float* maxat_fw = mean_bw + (size_t)B * L * H;
    float* maxat_bw = maxat_fw + (size_t)B * L * H;

    hipMemsetAsync(attsum, 0, 2048 * sizeof(float), stream);
    k_att_v3<<<dim3(B * 2, 8, 8), 64, 0, stream>>>(q1, q2, att_fw, att_bw, attsum);
    k_meanmax_v3<<<dim3(B * 2, 16), 256, 0, stream>>>(q2, att_fw, att_bw, attsum,
                                                      mean_fw, mean_bw, maxat_fw, maxat_bw);
    k_cosfull_v4<<<dim3(B * 16, 6), 256, 0, stream>>>(q1, q2, mean_fw, mean_bw,
                                                      maxat_fw, maxat_bw, W, out);
    k_maxpool_v5<<<dim3(B * 2, P), 256, 0, stream>>>(q1, q2, W, out);
}

// Round 12
// 135.689 us; speedup vs baseline: 1.2542x; 1.2542x over previous
//
#include <hip/hip_runtime.h>
#include <hip/hip_bf16.h>

#define B 16
#define L 128
#define H 256
#define H2 512
#define P 16
#define EPSF 1e-8f
#define LDSTR 72   // shorts per LDS row: 64 + 8 pad

typedef __attribute__((ext_vector_type(8))) short short8;
typedef __attribute__((ext_vector_type(4))) short short4v;
typedef __attribute__((ext_vector_type(4))) float f32x4;

__device__ __forceinline__ short f2bf(float x) {
    unsigned u = __builtin_bit_cast(unsigned, x);
    u += 0x7fffu + ((u >> 16) & 1u);   // RNE; inputs finite
    return (short)(u >> 16);
}
__device__ __forceinline__ float bf2f(short s) {
    unsigned u = ((unsigned)(unsigned short)s) << 16;
    return __builtin_bit_cast(float, u);
}
__device__ __forceinline__ short8 pack8(float4 x, float4 y) {
    short8 s;
    s[0] = f2bf(x.x); s[1] = f2bf(x.y); s[2] = f2bf(x.z); s[3] = f2bf(x.w);
    s[4] = f2bf(y.x); s[5] = f2bf(y.y); s[6] = f2bf(y.z); s[7] = f2bf(y.w);
    return s;
}
__device__ __forceinline__ float dot4(float4 v) {
    return v.x * v.x + v.y * v.y + v.z * v.z + v.w * v.w;
}
__device__ __forceinline__ float4 mul4(float4 a, float4 b) {
    return make_float4(a.x * b.x, a.y * b.y, a.z * b.z, a.w * b.w);
}

// ---- K1: attention, wave-per-16x16-tile, no LDS (R9-verbatim) --------------
__global__ void __launch_bounds__(64) k_att_v3(
        const float* __restrict__ q1, const float* __restrict__ q2,
        float* __restrict__ att_fw, float* __restrict__ att_bw,
        float* __restrict__ attsum) {
    int bx = blockIdx.x;
    int b = bx >> 1, dir = bx & 1;
    int m0 = blockIdx.y * 16, n0 = blockIdx.z * 16;
    int l = threadIdx.x, q = l >> 4, coll = l & 15;
    size_t bL = (size_t)b * L;

    const float* arow = q1 + (bL + m0 + coll) * H2 + dir * H;
    const float* brow = q2 + (bL + n0 + coll) * H2 + dir * H;

    f32x4 acc = (f32x4){0.f, 0.f, 0.f, 0.f};
    float na = 0.f, nc = 0.f;
#pragma unroll
    for (int ks = 0; ks < 8; ks++) {
        int koff = ks * 32 + q * 8;
        float4 a0 = *(const float4*)(arow + koff);
        float4 a1 = *(const float4*)(arow + koff + 4);
        float4 b0 = *(const float4*)(brow + koff);
        float4 b1 = *(const float4*)(brow + koff + 4);
        na += dot4(a0) + dot4(a1);
        nc += dot4(b0) + dot4(b1);
        short8 af = pack8(a0, a1);
        short8 bf = pack8(b0, b1);
        acc = __builtin_amdgcn_mfma_f32_16x16x32_bf16(af, bf, acc, 0, 0, 0);
    }
    na += __shfl_xor(na, 16); na += __shfl_xor(na, 32);
    nc += __shfl_xor(nc, 16); nc += __shfl_xor(nc, 32);
    float na_s = sqrtf(na), nc_s = sqrtf(nc);

    float* attout = dir ? att_bw : att_fw;
    float rsum[4];
#pragma unroll
    for (int r = 0; r < 4; r++) {
        float nar = __shfl(na_s, (l & 48) + q * 4 + r);
        float den = nar * nc_s;
        den = den > EPSF ? den : EPSF;
        float a = acc[r] / den;
        attout[(bL + m0 + q * 4 + r) * L + n0 + coll] = a;
        rsum[r] = a;
    }
    if (dir == 0) {
#pragma unroll
        for (int off = 1; off < 16; off <<= 1)
#pragma unroll
            for (int r = 0; r < 4; r++)
                rsum[r] += __shfl_xor(rsum[r], off, 16);
        if (coll == 0)
#pragma unroll
            for (int r = 0; r < 4; r++)
                atomicAdd(&attsum[bL + m0 + q * 4 + r], rsum[r]);
    }
}

// ---- K2: cos_maxpool (R9 maxpool_v2 verbatim) -------------------------------
// Grid (B*2, P, 2): (b,dir) x p x m-half. 256 thr, 4 waves (16 A-rows each).
__global__ void __launch_bounds__(256) k_maxpool_v2(
        const float* __restrict__ q1, const float* __restrict__ q2,
        const float* __restrict__ W, float* __restrict__ out) {
    int bd = blockIdx.x;
    int b = bd >> 1, dir = bd & 1;
    int p = blockIdx.y;
    int t = threadIdx.x;
    int wave = t >> 6, l = t & 63;
    int q = l >> 4, coll = l & 15;
    int m0 = blockIdx.z * 64 + wave * 16;
    size_t bL = (size_t)b * L;

    __shared__ short Bs[128 * LDSTR];
    __shared__ float wf[H];
    __shared__ float ncs[128];

    if (t < 64)
        *(float4*)(wf + t * 4) =
            *(const float4*)(W + ((size_t)(2 + dir) * P + p) * H + t * 4);
    __syncthreads();

    f32x4 acc[8];
#pragma unroll
    for (int nt = 0; nt < 8; nt++) acc[nt] = (f32x4){0.f, 0.f, 0.f, 0.f};
    float ncp = 0.f, nap = 0.f;

    int brow = t >> 1, bc0 = (t & 1) * 32;
    const float* q1b = q1 + bL * H2 + dir * H;
    const float* q2b = q2 + bL * H2 + dir * H;
    const float* arow = q1b + (size_t)(m0 + coll) * H2;
    const float* brp = q2b + (size_t)brow * H2;

    for (int kt = 0; kt < 4; kt++) {
        int k0 = kt * 64;
#pragma unroll
        for (int cc = 0; cc < 8; cc++) {
            float4 v = *(const float4*)(brp + k0 + bc0 + cc * 4);
            float4 wv4 = *(const float4*)(wf + k0 + bc0 + cc * 4);
            float4 x = mul4(v, wv4);
            short4v s = { f2bf(x.x), f2bf(x.y), f2bf(x.z), f2bf(x.w) };
            *(short4v*)(Bs + brow * LDSTR + bc0 + cc * 4) = s;
            float f0 = bf2f(s[0]), f1 = bf2f(s[1]), f2v = bf2f(s[2]), f3 = bf2f(s[3]);
            ncp += f0 * f0 + f1 * f1 + f2v * f2v + f3 * f3;
        }
        __syncthreads();
#pragma unroll
        for (int ks = 0; ks < 2; ks++) {
            int koff = ks * 32 + q * 8;
            float4 a0 = *(const float4*)(arow + k0 + koff);
            float4 a1 = *(const float4*)(arow + k0 + koff + 4);
            float4 w0 = *(const float4*)(wf + k0 + koff);
            float4 w1 = *(const float4*)(wf + k0 + koff + 4);
            float4 e0 = mul4(a0, w0), e1 = mul4(a1, w1);
            short8 af = pack8(e0, e1);
#pragma unroll
            for (int j = 0; j < 8; j++) {
                float f = bf2f(af[j]);
                nap += f * f;
            }
#pragma unroll
            for (int nt = 0; nt < 8; nt++) {
                short8 bf = *(const short8*)(Bs + (nt * 16 + coll) * LDSTR + koff);
                acc[nt] = __builtin_amdgcn_mfma_f32_16x16x32_bf16(af, bf, acc[nt], 0, 0, 0);
            }
        }
        __syncthreads();
    }
    ncp += __shfl_xor(ncp, 1);
    if ((t & 1) == 0) ncs[brow] = sqrtf(ncp);
    nap += __shfl_xor(nap, 16);
    nap += __shfl_xor(nap, 32);
    float na_s = sqrtf(nap);
    __syncthreads();

    float nar[4];
#pragma unroll
    for (int r = 0; r < 4; r++)
        nar[r] = __shfl(na_s, (l & 48) + q * 4 + r);
    float rmax[4] = {-INFINITY, -INFINITY, -INFINITY, -INFINITY};
#pragma unroll
    for (int nt = 0; nt < 8; nt++) {
        float ncv = ncs[nt * 16 + coll];
#pragma unroll
        for (int r = 0; r < 4; r++) {
            float den = fmaxf(nar[r] * ncv, EPSF);
            rmax[r] = fmaxf(rmax[r], acc[nt][r] / den);
        }
    }
#pragma unroll
    for (int off = 1; off < 16; off <<= 1)
#pragma unroll
        for (int r = 0; r < 4; r++)
            rmax[r] = fmaxf(rmax[r], __shfl_xor(rmax[r], off, 16));
    if (coll == 0)
#pragma unroll
        for (int r = 0; r < 4; r++)
            out[(bL + m0 + q * 4 + r) * 128 + 32 + dir * 16 + p] = rmax[r];
}

// ---- K3: FUSED meanmax (R11 math) + three dir-matched cos_full pieces ------
// Grid (B*2, 16): (b, dir, 8 i-rows). Phase 1 = meanmax into LDS;
// phase 2 = cos_full for pieces {q2-end, mean, maxat} of this dir.
__global__ void __launch_bounds__(256) k_mmcos(
        const float* __restrict__ q1, const float* __restrict__ q2,
        const float* __restrict__ att_fw, const float* __restrict__ att_bw,
        const float* __restrict__ attsum,
        const float* __restrict__ W, float* __restrict__ out) {
    int bd = blockIdx.x;
    int b = bd >> 1, dir = bd & 1;
    int i0 = blockIdx.y * 8;
    int t = threadIdx.x;
    int wave = t >> 6, l = t & 63;
    size_t bL = (size_t)b * L;

    __shared__ float at[8][L];
    __shared__ float Ss[8];
    __shared__ f32x4 red[4][64][4];
    __shared__ float meanL[8][H];
    __shared__ float maxL[8][H];

    const float* att = dir ? att_bw : att_fw;
    for (int v = t; v < 8 * L; v += 256)
        at[v >> 7][v & 127] = att[(bL + i0 + (v >> 7)) * L + (v & 127)];
    if (t < 8) {
        float s = attsum[bL + i0 + t];
        Ss[t] = s > EPSF ? s : EPSF;
    }
    __syncthreads();

    f32x4 sum[8], mx[8];
#pragma unroll
    for (int r = 0; r < 8; r++) {
        sum[r] = (f32x4){0.f, 0.f, 0.f, 0.f};
        mx[r] = (f32x4){-INFINITY, -INFINITY, -INFINITY, -INFINITY};
    }
    const float* q2b = q2 + bL * H2 + dir * H;
    for (int jj = 0; jj < 32; jj++) {
        int j = wave * 32 + jj;
        float4 c = *(const float4*)(q2b + (size_t)j * H2 + l * 4);
#pragma unroll
        for (int r = 0; r < 8; r++) {
            float w = at[r][j];
            f32x4 v = { w * c.x, w * c.y, w * c.z, w * c.w };
            sum[r] += v;
            mx[r][0] = fmaxf(mx[r][0], v[0]);
            mx[r][1] = fmaxf(mx[r][1], v[1]);
            mx[r][2] = fmaxf(mx[r][2], v[2]);
            mx[r][3] = fmaxf(mx[r][3], v[3]);
        }
    }
    for (int rr = 0; rr < 4; rr++) {
        __syncthreads();
        red[wave][l][0] = sum[rr * 2];
        red[wave][l][1] = mx[rr * 2];
        red[wave][l][2] = sum[rr * 2 + 1];
        red[wave][l][3] = mx[rr * 2 + 1];
        __syncthreads();
        if (t < 128) {
            int r2 = t >> 6;
            int lane = t & 63;
            f32x4 s = red[0][lane][r2 * 2];
            f32x4 m = red[0][lane][r2 * 2 + 1];
            for (int w = 1; w < 4; w++) {
                s += red[w][lane][r2 * 2];
                f32x4 m2 = red[w][lane][r2 * 2 + 1];
                m[0] = fmaxf(m[0], m2[0]);
                m[1] = fmaxf(m[1], m2[1]);
                m[2] = fmaxf(m[2], m2[2]);
                m[3] = fmaxf(m[3], m2[3]);
            }
            int r = rr * 2 + r2;
            float inv = 1.f / Ss[r];
            *(f32x4*)(&meanL[r][lane * 4]) = s * inv;
            *(f32x4*)(&maxL[r][lane * 4]) = m;
        }
    }
    __syncthreads();

    // ---- phase 2: cos_full (v4-identical summation), pieces of this dir ----
    int p = t >> 4, li = t & 15;
    // piece 0: c = q2 end-row (widx=dir, colb=16*dir)
    // piece 1: c = meanL      (widx=4+dir, colb=64+16*dir)
    // piece 2: c = maxL       (widx=6+dir, colb=96+16*dir)
    float4 wqA[4], wqB[4], wqC[4];
#pragma unroll
    for (int c = 0; c < 4; c++) {
        float4 wA = *(const float4*)(W + ((size_t)dir * P + p) * H + li * 16 + c * 4);
        float4 wB = *(const float4*)(W + ((size_t)(4 + dir) * P + p) * H + li * 16 + c * 4);
        float4 wC = *(const float4*)(W + ((size_t)(6 + dir) * P + p) * H + li * 16 + c * 4);
        wqA[c] = mul4(wA, wA);
        wqB[c] = mul4(wB, wB);
        wqC[c] = mul4(wC, wC);
    }
    const float* q2end = q2 + (bL + (dir ? 0 : (L - 1))) * H2 + dir * H + li * 16;
    float4 ce[4];
#pragma unroll
    for (int c = 0; c < 4; c++) ce[c] = *(const float4*)(q2end + c * 4);

    for (int ii = 0; ii < 8; ii++) {
        int i = i0 + ii;
        const float* r1 = q1 + (bL + i) * H2 + dir * H + li * 16;
        float4 a[4];
#pragma unroll
        for (int c = 0; c < 4; c++) a[c] = *(const float4*)(r1 + c * 4);

        float numA = 0, naA = 0, ncA = 0;
        float numB = 0, naB = 0, ncB = 0;
        float numC = 0, naC = 0, ncC = 0;
#pragma unroll
        for (int c = 0; c < 4; c++) {
            float4 cm = *(const float4*)(&meanL[ii][li * 16 + c * 4]);
            float4 cx = *(const float4*)(&maxL[ii][li * 16 + c * 4]);
            float4 av = a[c], cv = ce[c];
            numA += av.x * cv.x * wqA[c].x + av.y * cv.y * wqA[c].y
                  + av.z * cv.z * wqA[c].z + av.w * cv.w * wqA[c].w;
            naA  += av.x * av.x * wqA[c].x + av.y * av.y * wqA[c].y
                  + av.z * av.z * wqA[c].z + av.w * av.w * wqA[c].w;
            ncA  += cv.x * cv.x * wqA[c].x + cv.y * cv.y * wqA[c].y
                  + cv.z * cv.z * wqA[c].z + cv.w * cv.w * wqA[c].w;
            numB += av.x * cm.x * wqB[c].x + av.y * cm.y * wqB[c].y
                  + av.z * cm.z * wqB[c].z + av.w * cm.w * wqB[c].w;
            naB  += av.x * av.x * wqB[c].x + av.y * av.y * wqB[c].y
                  + av.z * av.z * wqB[c].z + av.w * av.w * wqB[c].w;
            ncB  += cm.x * cm.x * wqB[c].x + cm.y * cm.y * wqB[c].y
                  + cm.z * cm.z * wqB[c].z + cm.w * cm.w * wqB[c].w;
            numC += av.x * cx.x * wqC[c].x + av.y * cx.y * wqC[c].y
                  + av.z * cx.z * wqC[c].z + av.w * cx.w * wqC[c].w;
            naC  += av.x * av.x * wqC[c].x + av.y * av.y * wqC[c].y
                  + av.z * av.z * wqC[c].z + av.w * av.w * wqC[c].w;
            ncC  += cx.x * cx.x * wqC[c].x + cx.y * cx.y * wqC[c].y
                  + cx.z * cx.z * wqC[c].z + cx.w * cx.w * wqC[c].w;
        }
        for (int off = 8; off; off >>= 1) {
            numA += __shfl_down(numA, off, 16);
            naA  += __shfl_down(naA,  off, 16);
            ncA  += __shfl_down(ncA,  off, 16);
            numB += __shfl_down(numB, off, 16);
            naB  += __shfl_down(naB,  off, 16);
            ncB  += __shfl_down(ncB,  off, 16);
            numC += __shfl_down(numC, off, 16);
            naC  += __shfl_down(naC,  off, 16);
            ncC  += __shfl_down(ncC,  off, 16);
        }
        if (li == 0) {
            float dA = sqrtf(naA) * sqrtf(ncA); dA = dA > EPSF ? dA : EPSF;
            float dB = sqrtf(naB) * sqrtf(ncB); dB = dB > EPSF ? dB : EPSF;
            float dC = sqrtf(naC) * sqrtf(ncC); dC = dC > EPSF ? dC : EPSF;
            float* orow = out + (bL + i) * 128;
            orow[16 * dir + p] = numA / dA;
            orow[64 + 16 * dir + p] = numB / dB;
            orow[96 + 16 * dir + p] = numC / dC;
        }
    }
}

extern "C" void kernel_launch(void* const* d_in, const int* in_sizes, int n_in,
                              void* d_out, int out_size, void* d_ws, size_t ws_size,
                              hipStream_t stream) {
    const float* q1 = (const float*)d_in[0];
    const float* q2 = (const float*)d_in[1];
    const float* W  = (const float*)d_in[2];
    float* out = (float*)d_out;

    float* ws = (float*)d_ws;
    float* attsum = ws;                               // 2048
    float* att_fw = attsum + 2048;                    // B*L*L
    float* att_bw = att_fw + (size_t)B * L * L;

    hipMemsetAsync(attsum, 0, 2048 * sizeof(float), stream);
    k_att_v3<<<dim3(B * 2, 8, 8), 64, 0, stream>>>(q1, q2, att_fw, att_bw, attsum);
    k_maxpool_v2<<<dim3(B * 2, P, 2), 256, 0, stream>>>(q1, q2, W, out);
    k_mmcos<<<dim3(B * 2, 16), 256, 0, stream>>>(q1, q2, att_fw, att_bw, attsum,
                                                 W, out);
}